// Round 4
// baseline (554.150 us; speedup 1.0000x reference)
//
#include <hip/hip_runtime.h>
#include <hip/hip_bf16.h>
#include <hip/hip_fp16.h>
#include <math.h>

// ---------------------------------------------------------------------------
// 2-layer GAT on MI355X (gfx950).
// L1: in=128, H=8, C=32 (concat->256) +bias1, ELU.  L2: in=256, H=1, C=64 +bias2.
// R4: head-major sliced gather tables (h1p[8][N][32], h2p[2][N][32] fp16) with
// XCD-affine slice assignment (blockIdx&7 / blockIdx&1) so each XCD's gather
// set (3.2 MB) is L2-resident; exp(leaky()) numerators recomputed in-kernel
// (xs1/xs2 kernels and csr_dst eliminated).
// ---------------------------------------------------------------------------

#define LEAKY(e) ((e) > 0.f ? (e) : 0.2f * (e))

struct __align__(8) H4 { __half2 a, b; };  // 4 halves

// ------- tiled GEMM, fp32 in, fp16 sliced out -------------------------------
// Chp layout: [NTOT/32][n][32] (slice-major). 128x64 tile / 256 thr, 8x4 reg.
template <int K, int NTOT>
__global__ __launch_bounds__(256) void gemm_half_kernel(
    const float* __restrict__ A, const float* __restrict__ B,
    __half* __restrict__ Chp, int n) {
  const int KC = 64;
  __shared__ float As[KC][132];
  __shared__ float Bs[KC][68];
  int t = threadIdx.x;
  int tx = t & 15, ty = t >> 4;
  int m0 = blockIdx.x * 128;
  int c0 = blockIdx.y * 64;
  float acc[8][4] = {};
  for (int kc = 0; kc < K; kc += KC) {
#pragma unroll
    for (int rep = 0; rep < 8; rep++) {
      int lin = rep * 256 + t;
      int r = lin & 127;
      int k4 = (lin >> 7) * 4;
      int gr = m0 + r;
      float4 v = (gr < n) ? *(const float4*)(A + (size_t)gr * K + kc + k4)
                          : make_float4(0.f, 0.f, 0.f, 0.f);
      As[k4 + 0][r] = v.x;
      As[k4 + 1][r] = v.y;
      As[k4 + 2][r] = v.z;
      As[k4 + 3][r] = v.w;
    }
#pragma unroll
    for (int rep = 0; rep < 4; rep++) {
      int lin = rep * 256 + t;
      int r = lin >> 4;
      int c4 = (lin & 15) * 4;
      *(float4*)&Bs[r][c4] = *(const float4*)(B + (size_t)(kc + r) * NTOT + c0 + c4);
    }
    __syncthreads();
#pragma unroll 4
    for (int k = 0; k < KC; k++) {
      float4 a0 = *(const float4*)&As[k][ty * 8];
      float4 a1 = *(const float4*)&As[k][ty * 8 + 4];
      float4 b4 = *(const float4*)&Bs[k][tx * 4];
      float av[8] = {a0.x, a0.y, a0.z, a0.w, a1.x, a1.y, a1.z, a1.w};
      float bv[4] = {b4.x, b4.y, b4.z, b4.w};
#pragma unroll
      for (int i = 0; i < 8; i++)
#pragma unroll
        for (int j = 0; j < 4; j++) acc[i][j] = fmaf(av[i], bv[j], acc[i][j]);
    }
    __syncthreads();
  }
  int c = c0 + tx * 4;           // global output channel (4-aligned)
  int sl = c >> 5, wi = c & 31;  // slice, within-slice
#pragma unroll
  for (int i = 0; i < 8; i++) {
    int gr = m0 + ty * 8 + i;
    if (gr < n) {
      H4 hv;
      hv.a = __floats2half2_rn(acc[i][0], acc[i][1]);
      hv.b = __floats2half2_rn(acc[i][2], acc[i][3]);
      *(H4*)(Chp + ((size_t)sl * n + gr) * 32 + wi) = hv;
    }
  }
}

// --------- attention coefficients layer 1 (head-major): [8][N] -------------
__global__ __launch_bounds__(256) void att1_kernel(
    const __half* __restrict__ h1p, const float* __restrict__ att_src,
    const float* __restrict__ att_dst, float* __restrict__ a_srcp,
    float* __restrict__ a_dstp, int n) {
  int node = blockIdx.x * 256 + threadIdx.x;
  int h = blockIdx.y;
  if (node >= n) return;
  const H4* hp = (const H4*)(h1p + ((size_t)h * n + node) * 32);
  const float4* asp = (const float4*)(att_src + h * 32);
  const float4* adp = (const float4*)(att_dst + h * 32);
  float s = 0.f, d = 0.f;
#pragma unroll
  for (int q = 0; q < 8; q++) {
    H4 hv = hp[q];
    float2 p0 = __half22float2(hv.a), p1 = __half22float2(hv.b);
    float4 a = asp[q], b = adp[q];
    s += p0.x * a.x + p0.y * a.y + p1.x * a.z + p1.y * a.w;
    d += p0.x * b.x + p0.y * b.y + p1.x * b.z + p1.y * b.w;
  }
  a_srcp[(size_t)h * n + node] = s;
  a_dstp[(size_t)h * n + node] = d;
}

// --------- attention coefficients layer 2 (slice-major h2p): [N] -----------
__global__ __launch_bounds__(256) void att2_kernel(
    const __half* __restrict__ h2p, const float* __restrict__ att_src,
    const float* __restrict__ att_dst, float* __restrict__ a_src,
    float* __restrict__ a_dst, int n) {
  int node = blockIdx.x * 256 + threadIdx.x;
  if (node >= n) return;
  float s = 0.f, d = 0.f;
#pragma unroll
  for (int sl = 0; sl < 2; sl++) {
    const H4* hp = (const H4*)(h2p + ((size_t)sl * n + node) * 32);
#pragma unroll
    for (int q = 0; q < 8; q++) {
      H4 hv = hp[q];
      float2 p0 = __half22float2(hv.a), p1 = __half22float2(hv.b);
      float4 a = ((const float4*)att_src)[sl * 8 + q];
      float4 b = ((const float4*)att_dst)[sl * 8 + q];
      s += p0.x * a.x + p0.y * a.y + p1.x * a.z + p1.y * a.w;
      d += p0.x * b.x + p0.y * b.y + p1.x * b.z + p1.y * b.w;
    }
  }
  a_src[node] = s;
  a_dst[node] = d;
}

// ------------------------- CSR construction --------------------------------
__global__ __launch_bounds__(256) void hist_kernel(
    const int* __restrict__ ei, int E, int n, int* __restrict__ deg) {
  int idx = blockIdx.x * 256 + threadIdx.x;
  if (idx >= E + n) return;
  int d = (idx < E) ? ei[E + idx] : (idx - E);
  atomicAdd(&deg[d], 1);
}

__global__ __launch_bounds__(256) void scan1_kernel(
    const int* __restrict__ deg, int* __restrict__ bsum, int n) {
  __shared__ int ws[4];
  int t = threadIdx.x;
  int i = blockIdx.x * 256 + t;
  int v = (i < n) ? deg[i] : 0;
  int wv = v;
#pragma unroll
  for (int o = 32; o; o >>= 1) wv += __shfl_xor(wv, o, 64);
  if ((t & 63) == 0) ws[t >> 6] = wv;
  __syncthreads();
  if (t == 0) bsum[blockIdx.x] = ws[0] + ws[1] + ws[2] + ws[3];
}

__global__ __launch_bounds__(1024) void scan2_kernel(int* __restrict__ bsum,
                                                     int nb) {
  __shared__ int sb[1024];
  int t = threadIdx.x;
  int v = (t < nb) ? bsum[t] : 0;
  sb[t] = v;
  __syncthreads();
  int x = v;
  for (int off = 1; off < 1024; off <<= 1) {
    int y = (t >= off) ? sb[t - off] : 0;
    __syncthreads();
    x += y;
    sb[t] = x;
    __syncthreads();
  }
  if (t < nb) bsum[t] = x - v;  // exclusive
}

__global__ __launch_bounds__(256) void scan3_kernel(
    const int* __restrict__ deg, const int* __restrict__ bsum,
    int* __restrict__ rowptr, int* __restrict__ cursor, int n) {
  __shared__ int sb[256];
  int t = threadIdx.x;
  int i = blockIdx.x * 256 + t;
  int v = (i < n) ? deg[i] : 0;
  sb[t] = v;
  __syncthreads();
  int x = v;
  for (int off = 1; off < 256; off <<= 1) {
    int y = (t >= off) ? sb[t - off] : 0;
    __syncthreads();
    x += y;
    sb[t] = x;
    __syncthreads();
  }
  int excl = x - v + bsum[blockIdx.x];
  if (i < n) {
    rowptr[i] = excl;
    cursor[i] = excl;
  }
  if (i == n - 1) rowptr[n] = excl + v;
}

__global__ __launch_bounds__(256) void scatter_kernel(
    const int* __restrict__ ei, int E, int n, int* __restrict__ cursor,
    int* __restrict__ csr_src) {
  int idx = blockIdx.x * 256 + threadIdx.x;
  if (idx >= E + n) return;
  int s, d;
  if (idx < E) {
    s = ei[idx];
    d = ei[E + idx];
  } else {
    s = d = idx - E;
  }
  int pos = atomicAdd(&cursor[d], 1);
  csr_src[pos] = s;
}

// ------- layer-1 aggregation: wave = (dst, head); XCD-affine head ----------
// blockIdx.x = group*8 + head (round-robin dispatch -> head pinned per XCD).
// Main loop: 4 edge-slots x 16 lanes x half2 -> 64 B coalesced per edge.
__global__ __launch_bounds__(256) void agg1_kernel(
    const int* __restrict__ rowptr, const int* __restrict__ csr_src,
    const float* __restrict__ a_srcp, const float* __restrict__ a_dstp,
    const __half* __restrict__ h1p, const float* __restrict__ bias,
    float* __restrict__ h_act, int n) {
  int head = blockIdx.x & 7;
  int gidx = blockIdx.x >> 3;
  int w = threadIdx.x >> 6, l = threadIdx.x & 63;
  int d = gidx * 4 + w;
  if (d >= n) return;
  int base = rowptr[d], cnt = rowptr[d + 1] - base;
  const int* sp = csr_src + base;
  const float* asp = a_srcp + (size_t)head * n;
  float adst = a_dstp[(size_t)head * n + d];
  // softmax denominator (recompute exp; a_src slice is L2-resident)
  float p = 0.f;
  for (int i = l; i < cnt; i += 64) {
    float e = asp[sp[i]] + adst;
    e = LEAKY(e);
    p += __expf(e);
  }
#pragma unroll
  for (int o = 32; o; o >>= 1) p += __shfl_xor(p, o, 64);
  float rinv = 1.f / (p + 1e-16f);
  // message accumulate
  const __half* hp = h1p + (size_t)head * n * 32;
  int slot = l >> 4, c2 = (l & 15) * 2;
  float2 acc = make_float2(0.f, 0.f);
  for (int i = slot; i < cnt; i += 4) {
    int s = sp[i];
    float e = asp[s] + adst;
    e = LEAKY(e);
    float a = __expf(e) * rinv;
    float2 f = __half22float2(*(const __half2*)(hp + (size_t)s * 32 + c2));
    acc.x = fmaf(f.x, a, acc.x);
    acc.y = fmaf(f.y, a, acc.y);
  }
  acc.x += __shfl_xor(acc.x, 16, 64);
  acc.y += __shfl_xor(acc.y, 16, 64);
  acc.x += __shfl_xor(acc.x, 32, 64);
  acc.y += __shfl_xor(acc.y, 32, 64);
  if (l < 16) {
    float2 b = *(const float2*)(bias + head * 32 + c2);
    float ox = acc.x + b.x, oy = acc.y + b.y;
    ox = ox > 0.f ? ox : expm1f(ox);
    oy = oy > 0.f ? oy : expm1f(oy);
    *(float2*)(h_act + (size_t)d * 256 + head * 32 + c2) = make_float2(ox, oy);
  }
}

// ------- layer-2 aggregation: wave = (dst, 32-ch slice); XCD-parity slice --
__global__ __launch_bounds__(256) void agg2_kernel(
    const int* __restrict__ rowptr, const int* __restrict__ csr_src,
    const float* __restrict__ a_src, const float* __restrict__ a_dst,
    const __half* __restrict__ h2p, const float* __restrict__ bias,
    float* __restrict__ out, int n) {
  int slice = blockIdx.x & 1;
  int gidx = blockIdx.x >> 1;
  int w = threadIdx.x >> 6, l = threadIdx.x & 63;
  int d = gidx * 4 + w;
  if (d >= n) return;
  int base = rowptr[d], cnt = rowptr[d + 1] - base;
  const int* sp = csr_src + base;
  float adst = a_dst[d];
  float p = 0.f;
  for (int i = l; i < cnt; i += 64) {
    float e = a_src[sp[i]] + adst;
    e = LEAKY(e);
    p += __expf(e);
  }
#pragma unroll
  for (int o = 32; o; o >>= 1) p += __shfl_xor(p, o, 64);
  float rinv = 1.f / (p + 1e-16f);
  const __half* hp = h2p + (size_t)slice * n * 32;
  int slot = l >> 4, c2 = (l & 15) * 2;
  float2 acc = make_float2(0.f, 0.f);
  for (int i = slot; i < cnt; i += 4) {
    int s = sp[i];
    float e = a_src[s] + adst;
    e = LEAKY(e);
    float a = __expf(e) * rinv;
    float2 f = __half22float2(*(const __half2*)(hp + (size_t)s * 32 + c2));
    acc.x = fmaf(f.x, a, acc.x);
    acc.y = fmaf(f.y, a, acc.y);
  }
  acc.x += __shfl_xor(acc.x, 16, 64);
  acc.y += __shfl_xor(acc.y, 16, 64);
  acc.x += __shfl_xor(acc.x, 32, 64);
  acc.y += __shfl_xor(acc.y, 32, 64);
  if (l < 16) {
    int c = slice * 32 + c2;
    float2 b = *(const float2*)(bias + c);
    *(float2*)(out + (size_t)d * 64 + c) = make_float2(acc.x + b.x, acc.y + b.y);
  }
}

// ---------------------------------------------------------------------------
extern "C" void kernel_launch(void* const* d_in, const int* in_sizes, int n_in,
                              void* d_out, int out_size, void* d_ws, size_t ws_size,
                              hipStream_t stream) {
  const float* x        = (const float*)d_in[0];
  const int*   ei       = (const int*)d_in[1];
  const float* W1       = (const float*)d_in[3];
  const float* att_src1 = (const float*)d_in[4];
  const float* att_dst1 = (const float*)d_in[5];
  const float* bias1    = (const float*)d_in[6];
  const float* W2       = (const float*)d_in[7];
  const float* att_src2 = (const float*)d_in[8];
  const float* att_dst2 = (const float*)d_in[9];
  const float* bias2    = (const float*)d_in[10];
  float* out = (float*)d_out;

  int N = in_sizes[0] / 128;
  int E = in_sizes[1] / 2;
  int Etot = E + N;
  int nb = (N + 255) / 256;

  char* ws = (char*)d_ws;
  size_t off = 0;
  auto carve = [&](size_t bytes) -> void* {
    void* p = ws + off;
    off += (bytes + 255) & ~(size_t)255;
    return p;
  };
  __half* h1p   = (__half*)carve((size_t)N * 256 * 2);  // [8][N][32]
  __half* h2p   = (__half*)carve((size_t)N * 64 * 2);   // [2][N][32]
  float* h_act  = (float*)carve((size_t)N * 256 * 4);
  float* a_src1 = (float*)carve((size_t)N * 8 * 4);     // [8][N]
  float* a_dst1 = (float*)carve((size_t)N * 8 * 4);     // [8][N]
  float* a_src2 = (float*)carve((size_t)N * 4);
  float* a_dst2 = (float*)carve((size_t)N * 4);
  int* rowptr   = (int*)carve((size_t)(N + 1) * 4);
  int* cursor   = (int*)carve((size_t)N * 4);
  int* deg      = (int*)carve((size_t)N * 4);
  int* bsum     = (int*)carve((size_t)nb * 4);
  int* csr_src  = (int*)carve((size_t)Etot * 4);
  (void)ws_size; (void)n_in; (void)out_size;

  // layer-1 projection (fp16 head-major out) + attention coefficients
  {
    dim3 g((N + 127) / 128, 4);
    gemm_half_kernel<128, 256><<<g, 256, 0, stream>>>(x, W1, h1p, N);
  }
  {
    dim3 g((N + 255) / 256, 8);
    att1_kernel<<<g, 256, 0, stream>>>(h1p, att_src1, att_dst1, a_src1, a_dst1, N);
  }
  // CSR build
  hipMemsetAsync(deg, 0, (size_t)N * 4, stream);
  hist_kernel<<<(Etot + 255) / 256, 256, 0, stream>>>(ei, E, N, deg);
  scan1_kernel<<<nb, 256, 0, stream>>>(deg, bsum, N);
  scan2_kernel<<<1, 1024, 0, stream>>>(bsum, nb);
  scan3_kernel<<<nb, 256, 0, stream>>>(deg, bsum, rowptr, cursor, N);
  scatter_kernel<<<(Etot + 255) / 256, 256, 0, stream>>>(ei, E, N, cursor, csr_src);
  // layer-1 aggregation (+bias+ELU)
  agg1_kernel<<<((N + 3) / 4) * 8, 256, 0, stream>>>(rowptr, csr_src, a_src1,
                                                     a_dst1, h1p, bias1, h_act, N);
  // layer 2
  {
    dim3 g((N + 127) / 128, 1);
    gemm_half_kernel<256, 64><<<g, 256, 0, stream>>>(h_act, W2, h2p, N);
  }
  att2_kernel<<<(N + 255) / 256, 256, 0, stream>>>(h2p, att_src2, att_dst2,
                                                   a_src2, a_dst2, N);
  agg2_kernel<<<((N + 3) / 4) * 2, 256, 0, stream>>>(rowptr, csr_src, a_src2,
                                                     a_dst2, h2p, bias2, out, N);
}